// Round 10
// baseline (100.301 us; speedup 1.0000x reference)
//
#include <hip/hip_runtime.h>

// ApproxNDCGLoss, N=20000, fp32 — TWO dispatches; FULLY-sorted ybkt => index
// IS the rank; consume's divergent rank scan eliminated.
//
// R9 post-mortem: 1024-thr consume REGRESSED (73.9 -> 75.9) — revert to R8's
// 79x256. Remaining modeled cost in consume: the rank scan — per-element
// runtime-trip loop, 64-way divergent, uncoalesced 4B loads (~10-20 iters).
// It exists only to recover exact rank. Equivalence: if g_ybkt is FULLY
// sorted, index==rank: idcg term = ybkt[j]/log2(n-j+1), coalesced, no loop.
// Cost moved to produce blk0: within-bucket LDS insertion sort (avg 9.8
// elems/bucket, 2 buckets/thread ~ 1-2 us) — NOT the R5 trap (that was
// per-element f64 log2 + full scan on one CU). Also now tie-exact (matches
// reference sort semantics; strict-greater formula assumed distinct y).
//
// Unchanged from verified R8: histogram, shuffle scan, LDS scatter, coalesced
// copy-out, node blocks, barycentric dcg, ticket finalize, self-clean.
// Decision rule: Δ < 2 us vs 73.9 => declare roofline (39.5 fill + 2 minimal
// kernels + ~3 boundaries is the structural floor).

#define LOG2E 1.442695040888963387f
#define M_NODES 64
#define XHALF 8.0
#define NB 2048
#define PI_D 3.14159265358979323846
#define BT 1024
#define CT 256
#define LDS_N 20480
#define MAXN 131072

#if __has_builtin(__builtin_amdgcn_exp2f)
#define EXP2(x) __builtin_amdgcn_exp2f(x)
#else
#define EXP2(x) exp2f(x)
#endif

#if __has_builtin(__builtin_amdgcn_rcpf)
#define RCP(x) __builtin_amdgcn_rcpf(x)
#else
#define RCP(x) (1.0f / (x))
#endif

// ---- module-global state (poison-free; visibility via kernel boundary) ----
__device__ double g_acc[3] = {0.0, 0.0, 0.0};  // dcg, idcg, ysum
__device__ int g_done = 0;
__device__ float2 g_nodes[M_NODES];  // (x_k, F_k)
__device__ int g_prefix[NB + 1];     // bucket starts (fallback path only)
__device__ float g_ybkt[MAXN];       // FULLY sorted y (ascending)

__device__ __forceinline__ int bucket_of(float y) {
  int b = (int)(y * (float)NB);
  return b < 0 ? 0 : (b > NB - 1 ? NB - 1 : b);
}

// ---- produce: blk 0 = full sort (LDS); blk 1..64 = Chebyshev nodes ----
__global__ __launch_bounds__(BT) void produce_kernel(
    const float* __restrict__ s, const float* __restrict__ y, int n) {
  const int tid = threadIdx.x;
  const int blk = blockIdx.x;
  const int lane = tid & 63;

  __shared__ int hist[NB];         // histogram -> scatter cursor -> bucket end
  __shared__ int sbeg[NB];         // bucket starts (8 KB)
  __shared__ float ybkt_l[LDS_N];  // LDS scatter/sort arena (80 KB)
  __shared__ int wrep[16];         // scan wave partials
  __shared__ double wsum[16];      // node reduction scratch

  if (blk == 0) {
    // --- histogram ---
    for (int b = tid; b < NB; b += BT) hist[b] = 0;
    __syncthreads();

    const float4* y4 = (const float4*)y;
    const int n4 = n >> 2;
    for (int i = tid; i < n4; i += BT) {
      const float4 v = y4[i];
      atomicAdd(&hist[bucket_of(v.x)], 1);
      atomicAdd(&hist[bucket_of(v.y)], 1);
      atomicAdd(&hist[bucket_of(v.z)], 1);
      atomicAdd(&hist[bucket_of(v.w)], 1);
    }
    for (int i = (n4 << 2) + tid; i < n; i += BT)
      atomicAdd(&hist[bucket_of(y[i])], 1);
    __syncthreads();

    // --- exclusive scan (2 bins/thread), shuffle-based, 2 barriers ---
    const int base = tid * 2;
    const int l0 = hist[base], l1 = hist[base + 1];
    const int sum2 = l0 + l1;
    int v = sum2;
#pragma unroll
    for (int d = 1; d < 64; d <<= 1) {
      const int t = __shfl_up(v, d);
      if (lane >= d) v += t;
    }
    if (lane == 63) wrep[tid >> 6] = v;
    __syncthreads();
    if (tid < 16) {
      int wv = wrep[tid];
#pragma unroll
      for (int d = 1; d < 16; d <<= 1) {
        const int t = __shfl_up(wv, d);
        if (tid >= d) wv += t;
      }
      wrep[tid] = wv;
    }
    __syncthreads();
    const int wbase = (tid >> 6) ? wrep[(tid >> 6) - 1] : 0;
    const int incl = wbase + v;
    const int run = incl - sum2;  // exclusive prefix of this 2-bin chunk
    g_prefix[base] = run;         // kept for the n>LDS_N fallback path
    g_prefix[base + 1] = run + l0;
    if (tid == BT - 1) g_prefix[NB] = incl;  // == n
    sbeg[base] = run;             // bucket starts (for in-bucket sort)
    sbeg[base + 1] = run + l0;
    hist[base] = run;             // scatter cursor
    hist[base + 1] = run + l0;
    __syncthreads();

    if (n <= LDS_N) {
      // --- scatter into LDS ---
      for (int i = tid; i < n4; i += BT) {
        const float4 v4 = y4[i];
        ybkt_l[atomicAdd(&hist[bucket_of(v4.x)], 1)] = v4.x;
        ybkt_l[atomicAdd(&hist[bucket_of(v4.y)], 1)] = v4.y;
        ybkt_l[atomicAdd(&hist[bucket_of(v4.z)], 1)] = v4.z;
        ybkt_l[atomicAdd(&hist[bucket_of(v4.w)], 1)] = v4.w;
      }
      for (int i = (n4 << 2) + tid; i < n; i += BT) {
        const float yv = y[i];
        ybkt_l[atomicAdd(&hist[bucket_of(yv)], 1)] = yv;
      }
      __syncthreads();  // scatter complete; hist[b] now == bucket end

      // --- within-bucket insertion sort (2 buckets/thread, ~10 elems avg) ---
#pragma unroll
      for (int q = 0; q < 2; ++q) {
        const int b = base + q;
        const int lo = sbeg[b], hi = hist[b];
        for (int i = lo + 1; i < hi; ++i) {
          const float vv = ybkt_l[i];
          int k = i - 1;
          while (k >= lo && ybkt_l[k] > vv) {
            ybkt_l[k + 1] = ybkt_l[k];
            --k;
          }
          ybkt_l[k + 1] = vv;
        }
      }
      __syncthreads();

      // --- coalesced copy-out: float4 line-aligned wave stores ---
      const int nv = (n + 3) >> 2;  // tail lanes copy unused LDS — harmless
      float4* gb4 = (float4*)g_ybkt;
      const float4* lb4 = (const float4*)ybkt_l;
      for (int i = tid; i < nv; i += BT) gb4[i] = lb4[i];
    } else {
      // fallback (n > LDS_N): global scatter, then global in-bucket sort
      for (int i = tid; i < n4; i += BT) {
        const float4 v4 = y4[i];
        g_ybkt[atomicAdd(&hist[bucket_of(v4.x)], 1)] = v4.x;
        g_ybkt[atomicAdd(&hist[bucket_of(v4.y)], 1)] = v4.y;
        g_ybkt[atomicAdd(&hist[bucket_of(v4.z)], 1)] = v4.z;
        g_ybkt[atomicAdd(&hist[bucket_of(v4.w)], 1)] = v4.w;
      }
      for (int i = (n4 << 2) + tid; i < n; i += BT) {
        const float yv = y[i];
        g_ybkt[atomicAdd(&hist[bucket_of(yv)], 1)] = yv;
      }
      __syncthreads();
#pragma unroll
      for (int q = 0; q < 2; ++q) {
        const int b = base + q;
        const int lo = g_prefix[b], hi = hist[b];
        for (int i = lo + 1; i < hi; ++i) {
          const float vv = g_ybkt[i];
          int k = i - 1;
          while (k >= lo && g_ybkt[k] > vv) {
            g_ybkt[k + 1] = g_ybkt[k];
            --k;
          }
          g_ybkt[k + 1] = vv;
        }
      }
    }
  } else {
    // --- node k: F(x_k) = sum_i sigmoid(x_k - s_i) (verified math) ---
    const int k = blk - 1;
    const float xk =
        (float)(XHALF * cos(PI_D * (double)k / (double)(M_NODES - 1)));
    double F = 0.0;
    const float4* s4 = (const float4*)s;
    const int n4 = n >> 2;
    for (int i = tid; i < n4; i += BT) {
      const float4 v = s4[i];
      float t = RCP(1.0f + EXP2((v.x - xk) * LOG2E));
      t += RCP(1.0f + EXP2((v.y - xk) * LOG2E));
      t += RCP(1.0f + EXP2((v.z - xk) * LOG2E));
      t += RCP(1.0f + EXP2((v.w - xk) * LOG2E));
      F += (double)t;
    }
    for (int i = (n4 << 2) + tid; i < n; i += BT)
      F += (double)RCP(1.0f + EXP2((s[i] - xk) * LOG2E));
    for (int off = 32; off > 0; off >>= 1) F += __shfl_down(F, off);
    if (lane == 0) wsum[tid >> 6] = F;
    __syncthreads();
    if (tid == 0) {
      double t = 0.0;
#pragma unroll
      for (int w = 0; w < 16; ++w) t += wsum[w];
      g_nodes[k] = make_float2(xk, (float)t);
    }
  }
}

// ---- consume: barycentric dcg + sorted-index idcg + finalize (79x256) ----
__global__ __launch_bounds__(CT) void consume_kernel(
    const float* __restrict__ s, const float* __restrict__ y,
    float* __restrict__ out, int n, int nblocks) {
  __shared__ float2 nd[M_NODES];
  __shared__ double wsum[12];
  const int tid = threadIdx.x;
  if (tid < M_NODES) nd[tid] = g_nodes[tid];
  __syncthreads();

  const int j = blockIdx.x * CT + tid;
  double dc = 0.0, ic = 0.0, ys = 0.0;
  if (j < n) {
    const float x = s[j];
    const float yj = y[j];

    // dcg: barycentric interpolation of F(s_j) over 64 Chebyshev nodes
    double num = 0.0, den = 0.0;
    int hit = -1;
#pragma unroll
    for (int k = 0; k < M_NODES; ++k) {
      const float d = x - nd[k].x;
      float w = (k & 1) ? -1.0f : 1.0f;
      if (k == 0 || k == M_NODES - 1) w *= 0.5f;
      if (d == 0.0f) {
        hit = k;
      } else {
        const float iv = w * RCP(d);
        num += (double)iv * (double)nd[k].y;
        den += (double)iv;
      }
    }
    const double F = (hit >= 0) ? (double)nd[hit].y : (num / den);
    dc = (double)yj / log2(F + 2.0);

    // idcg: g_ybkt fully sorted ascending => descending rank of index j is
    // (n-1-j) 0-based; discount = 1/log2(rank+2) = 1/log2(n-j+1). Coalesced.
    const float yv = g_ybkt[j];
    ic = (double)yv / log2((double)(n - j) + 1.0);

    ys = (double)yj;
  }
  for (int off = 32; off > 0; off >>= 1) {
    dc += __shfl_down(dc, off);
    ic += __shfl_down(ic, off);
    ys += __shfl_down(ys, off);
  }
  const int wv = tid >> 6;
  if ((tid & 63) == 0) {
    wsum[wv] = dc;
    wsum[wv + 4] = ic;
    wsum[wv + 8] = ys;
  }
  __syncthreads();
  if (tid == 0) {
    atomicAdd(&g_acc[0], wsum[0] + wsum[1] + wsum[2] + wsum[3]);
    atomicAdd(&g_acc[1], wsum[4] + wsum[5] + wsum[6] + wsum[7]);
    atomicAdd(&g_acc[2], wsum[8] + wsum[9] + wsum[10] + wsum[11]);
    __threadfence();
    const int old = atomicAdd(&g_done, 1);
    if (old == nblocks - 1) {  // last block: all acc updates visible
      const double dcg = atomicAdd(&g_acc[0], 0.0);
      const double idcg = atomicAdd(&g_acc[1], 0.0);
      const double ysum = atomicAdd(&g_acc[2], 0.0);
      const double loss = 1.0 - dcg / (idcg + 1e-8);
      out[0] = (ysum < 1.0) ? 0.0f : (float)loss;
      // self-clean for next replay (visible via kernel boundary)
      g_acc[0] = 0.0;
      g_acc[1] = 0.0;
      g_acc[2] = 0.0;
      g_done = 0;
      __threadfence();
    }
  }
}

extern "C" void kernel_launch(void* const* d_in, const int* in_sizes, int n_in,
                              void* d_out, int out_size, void* d_ws,
                              size_t ws_size, hipStream_t stream) {
  const float* s = (const float*)d_in[0];
  const float* y = (const float*)d_in[1];
  const int n = in_sizes[0];
  (void)d_ws;
  (void)ws_size;  // ws poison is unconditional; module globals are poison-free

  const int nb = (n + CT - 1) / CT;  // 79 blocks @ n=20000 (R8 best shape)
  produce_kernel<<<M_NODES + 1, BT, 0, stream>>>(s, y, n);
  consume_kernel<<<nb, CT, 0, stream>>>(s, y, (float*)d_out, n, nb);
}

// Round 11
// 73.415 us; speedup vs baseline: 1.3662x; 1.3662x over previous
//
#include <hip/hip_runtime.h>

// ApproxNDCGLoss, N=20000, fp32 — TWO dispatches; R8 structure + NB=8192.
//
// R10 post-mortem: in-produce insertion sort = 43 us produce (serial
// dependent-LDS chains + wave-lockstep divergence on block 0's single CU;
// same family as the R5 trap). REVERTED to R8 (best verified, 73.9).
//
// Budget (from R1/R5/R6/R8 cross-round arithmetic): 39.5 fill + ~17.5 gaps
// (3 boundaries x ~6) + produce ~6 + consume ~11, of which the divergent
// rank scan ~6-8. R11 change (one parameter): NB 2048 -> 8192. Avg bucket
// 9.77 -> 2.44, wave-max trip ~25 -> ~9 => scan cost /2.5 statistically.
// Produce: hist LDS 32 KB (total ~112 KB, still 1 blk/CU), scan becomes
// 8 bins/thread (same 2-barrier shuffle structure), atomics spread over 4x
// buckets (less same-address contention). Consume code unchanged; rank
// semantics identical => absmax stays 0.0.
//
// Decision rule: Δ < 2 us vs 73.9 => declare roofline (fill + boundary
// overhead + kernel floor is structural).

#define LOG2E 1.442695040888963387f
#define M_NODES 64
#define XHALF 8.0
#define NB 8192
#define BPT 8  // NB / BT bins per thread in the scan
#define PI_D 3.14159265358979323846
#define BT 1024
#define CT 256
#define LDS_N 20480
#define MAXN 131072

#if __has_builtin(__builtin_amdgcn_exp2f)
#define EXP2(x) __builtin_amdgcn_exp2f(x)
#else
#define EXP2(x) exp2f(x)
#endif

#if __has_builtin(__builtin_amdgcn_rcpf)
#define RCP(x) __builtin_amdgcn_rcpf(x)
#else
#define RCP(x) (1.0f / (x))
#endif

// ---- module-global state (poison-free; visibility via kernel boundary) ----
__device__ double g_acc[3] = {0.0, 0.0, 0.0};  // dcg, idcg, ysum
__device__ int g_done = 0;
__device__ float2 g_nodes[M_NODES];  // (x_k, F_k)
__device__ int g_prefix[NB + 1];     // bucket starts
__device__ float g_ybkt[MAXN];       // bucket-sorted y

__device__ __forceinline__ int bucket_of(float y) {
  int b = (int)(y * (float)NB);
  return b < 0 ? 0 : (b > NB - 1 ? NB - 1 : b);
}

// ---- produce: blk 0 = sort (LDS scatter, coalesced out); blk 1..64 = nodes
__global__ __launch_bounds__(BT) void produce_kernel(
    const float* __restrict__ s, const float* __restrict__ y, int n) {
  const int tid = threadIdx.x;
  const int blk = blockIdx.x;
  const int lane = tid & 63;

  __shared__ int hist[NB];          // histogram, then scatter cursor (32 KB)
  __shared__ float ybkt_l[LDS_N];   // LDS scatter target (80 KB)
  __shared__ int wrep[16];          // scan wave partials
  __shared__ double wsum[16];       // node reduction scratch

  if (blk == 0) {
    // --- histogram ---
    for (int b = tid; b < NB; b += BT) hist[b] = 0;
    __syncthreads();

    const float4* y4 = (const float4*)y;
    const int n4 = n >> 2;
    for (int i = tid; i < n4; i += BT) {
      const float4 v = y4[i];
      atomicAdd(&hist[bucket_of(v.x)], 1);
      atomicAdd(&hist[bucket_of(v.y)], 1);
      atomicAdd(&hist[bucket_of(v.z)], 1);
      atomicAdd(&hist[bucket_of(v.w)], 1);
    }
    for (int i = (n4 << 2) + tid; i < n; i += BT)
      atomicAdd(&hist[bucket_of(y[i])], 1);
    __syncthreads();

    // --- exclusive scan (BPT bins/thread), shuffle-based, 2 barriers ---
    const int base = tid * BPT;
    int c[BPT];
    int sumB = 0;
#pragma unroll
    for (int q = 0; q < BPT; ++q) {
      c[q] = hist[base + q];
      sumB += c[q];
    }
    int v = sumB;  // inclusive scan of per-thread sums within wave
#pragma unroll
    for (int d = 1; d < 64; d <<= 1) {
      const int t = __shfl_up(v, d);
      if (lane >= d) v += t;
    }
    if (lane == 63) wrep[tid >> 6] = v;
    __syncthreads();
    if (tid < 16) {
      int wv = wrep[tid];
#pragma unroll
      for (int d = 1; d < 16; d <<= 1) {
        const int t = __shfl_up(wv, d);
        if (tid >= d) wv += t;
      }
      wrep[tid] = wv;
    }
    __syncthreads();
    const int wbase = (tid >> 6) ? wrep[(tid >> 6) - 1] : 0;
    const int incl = wbase + v;
    int p = incl - sumB;  // exclusive start of bin `base`
#pragma unroll
    for (int q = 0; q < BPT; ++q) {
      g_prefix[base + q] = p;  // publish (boundary makes it visible)
      hist[base + q] = p;      // LDS scatter cursor
      p += c[q];
    }
    if (tid == BT - 1) g_prefix[NB] = p;  // == n
    __syncthreads();

    if (n <= LDS_N) {
      // --- scatter into LDS (random 4B writes at bank speed) ---
      for (int i = tid; i < n4; i += BT) {
        const float4 v4 = y4[i];
        ybkt_l[atomicAdd(&hist[bucket_of(v4.x)], 1)] = v4.x;
        ybkt_l[atomicAdd(&hist[bucket_of(v4.y)], 1)] = v4.y;
        ybkt_l[atomicAdd(&hist[bucket_of(v4.z)], 1)] = v4.z;
        ybkt_l[atomicAdd(&hist[bucket_of(v4.w)], 1)] = v4.w;
      }
      for (int i = (n4 << 2) + tid; i < n; i += BT) {
        const float yv = y[i];
        ybkt_l[atomicAdd(&hist[bucket_of(yv)], 1)] = yv;
      }
      __syncthreads();
      // --- coalesced copy-out: float4 line-aligned wave stores ---
      const int nv = (n + 3) >> 2;  // tail lanes copy unused LDS — harmless
      float4* gb4 = (float4*)g_ybkt;
      const float4* lb4 = (const float4*)ybkt_l;
      for (int i = tid; i < nv; i += BT) gb4[i] = lb4[i];
    } else {
      // fallback (n > LDS_N): direct global scatter as in R6
      for (int i = tid; i < n4; i += BT) {
        const float4 v4 = y4[i];
        g_ybkt[atomicAdd(&hist[bucket_of(v4.x)], 1)] = v4.x;
        g_ybkt[atomicAdd(&hist[bucket_of(v4.y)], 1)] = v4.y;
        g_ybkt[atomicAdd(&hist[bucket_of(v4.z)], 1)] = v4.z;
        g_ybkt[atomicAdd(&hist[bucket_of(v4.w)], 1)] = v4.w;
      }
      for (int i = (n4 << 2) + tid; i < n; i += BT) {
        const float yv = y[i];
        g_ybkt[atomicAdd(&hist[bucket_of(yv)], 1)] = yv;
      }
    }
  } else {
    // --- node k: F(x_k) = sum_i sigmoid(x_k - s_i) (verified math) ---
    const int k = blk - 1;
    const float xk =
        (float)(XHALF * cos(PI_D * (double)k / (double)(M_NODES - 1)));
    double F = 0.0;
    const float4* s4 = (const float4*)s;
    const int n4 = n >> 2;
    for (int i = tid; i < n4; i += BT) {
      const float4 v = s4[i];
      float t = RCP(1.0f + EXP2((v.x - xk) * LOG2E));
      t += RCP(1.0f + EXP2((v.y - xk) * LOG2E));
      t += RCP(1.0f + EXP2((v.z - xk) * LOG2E));
      t += RCP(1.0f + EXP2((v.w - xk) * LOG2E));
      F += (double)t;
    }
    for (int i = (n4 << 2) + tid; i < n; i += BT)
      F += (double)RCP(1.0f + EXP2((s[i] - xk) * LOG2E));
    for (int off = 32; off > 0; off >>= 1) F += __shfl_down(F, off);
    if (lane == 0) wsum[tid >> 6] = F;
    __syncthreads();
    if (tid == 0) {
      double t = 0.0;
#pragma unroll
      for (int w = 0; w < 16; ++w) t += wsum[w];
      g_nodes[k] = make_float2(xk, (float)t);
    }
  }
}

// ---- consume: barycentric dcg + parallel rank-scan idcg + finalize ----
__global__ __launch_bounds__(CT) void consume_kernel(
    const float* __restrict__ s, const float* __restrict__ y,
    float* __restrict__ out, int n, int nblocks) {
  __shared__ float2 nd[M_NODES];
  __shared__ double wsum[12];
  const int tid = threadIdx.x;
  if (tid < M_NODES) nd[tid] = g_nodes[tid];
  __syncthreads();

  const int j = blockIdx.x * CT + tid;
  double dc = 0.0, ic = 0.0, ys = 0.0;
  if (j < n) {
    const float x = s[j];
    const float yj = y[j];
    // dcg: barycentric interpolation of F(s_j) over 64 Chebyshev nodes
    double num = 0.0, den = 0.0;
    int hit = -1;
#pragma unroll
    for (int k = 0; k < M_NODES; ++k) {
      const float d = x - nd[k].x;
      float w = (k & 1) ? -1.0f : 1.0f;
      if (k == 0 || k == M_NODES - 1) w *= 0.5f;
      if (d == 0.0f) {
        hit = k;
      } else {
        const float iv = w * RCP(d);
        num += (double)iv * (double)nd[k].y;
        den += (double)iv;
      }
    }
    const double F = (hit >= 0) ? (double)nd[hit].y : (num / den);

    // idcg: exact rank = 1 + #(strictly greater); short L2 bucket scan
    const int b = bucket_of(yj);
    const int s0 = g_prefix[b];
    const int s1 = g_prefix[b + 1];
    int cnt = n - s1;  // strictly higher buckets
    for (int t = s0; t < s1; ++t) cnt += (g_ybkt[t] > yj);

    dc = (double)yj / log2(F + 2.0);
    ic = (double)yj / log2((double)cnt + 2.0);
    ys = (double)yj;
  }
  for (int off = 32; off > 0; off >>= 1) {
    dc += __shfl_down(dc, off);
    ic += __shfl_down(ic, off);
    ys += __shfl_down(ys, off);
  }
  const int wv = tid >> 6;
  if ((tid & 63) == 0) {
    wsum[wv] = dc;
    wsum[wv + 4] = ic;
    wsum[wv + 8] = ys;
  }
  __syncthreads();
  if (tid == 0) {
    atomicAdd(&g_acc[0], wsum[0] + wsum[1] + wsum[2] + wsum[3]);
    atomicAdd(&g_acc[1], wsum[4] + wsum[5] + wsum[6] + wsum[7]);
    atomicAdd(&g_acc[2], wsum[8] + wsum[9] + wsum[10] + wsum[11]);
    __threadfence();
    const int old = atomicAdd(&g_done, 1);
    if (old == nblocks - 1) {  // last block: all acc updates visible
      const double dcg = atomicAdd(&g_acc[0], 0.0);
      const double idcg = atomicAdd(&g_acc[1], 0.0);
      const double ysum = atomicAdd(&g_acc[2], 0.0);
      const double loss = 1.0 - dcg / (idcg + 1e-8);
      out[0] = (ysum < 1.0) ? 0.0f : (float)loss;
      // self-clean for next replay (visible via kernel boundary)
      g_acc[0] = 0.0;
      g_acc[1] = 0.0;
      g_acc[2] = 0.0;
      g_done = 0;
      __threadfence();
    }
  }
}

extern "C" void kernel_launch(void* const* d_in, const int* in_sizes, int n_in,
                              void* d_out, int out_size, void* d_ws,
                              size_t ws_size, hipStream_t stream) {
  const float* s = (const float*)d_in[0];
  const float* y = (const float*)d_in[1];
  const int n = in_sizes[0];
  (void)d_ws;
  (void)ws_size;  // ws poison is unconditional; module globals are poison-free

  const int nb = (n + CT - 1) / CT;  // 79 blocks @ n=20000 (R8 best shape)
  produce_kernel<<<M_NODES + 1, BT, 0, stream>>>(s, y, n);
  consume_kernel<<<nb, CT, 0, stream>>>(s, y, (float*)d_out, n, nb);
}